// Round 1
// baseline (575.974 us; speedup 1.0000x reference)
//
#include <hip/hip_runtime.h>
#include <math.h>

// ---- problem constants ----
// B=8, H=W=D=32, V=32768 per batch, S=64
// outputs (flat, in return order):
//   sampled [8,32,32,32]         -> 262144  @ 0
//   E       [8,3,3]              -> 72      @ 262144
//   coords  [8,32,32,32,3]       -> 786432  @ 262216
//   points_code [8,32768,384]    -> 100663296 @ 1048648
#define OFF_E     262144
#define OFF_COORD 262216
#define OFF_CODE  1048648

#define QUAD 0.19634954084936207f   // 4*pi/64

// ---- ws layout (floats) ----
// wsH1: [8,64,64]   @ 0        (32768)
// wsH2: [8,64,128]  @ 32768    (65536)
// wsC:  [8,16,64]   @ 98304    (8192)
// wsAB: [8,18]      @ 106496   (144)
#define WS_H1 0
#define WS_H2 32768
#define WS_C  98304
#define WS_AB 106496

// ============================================================
// Kernel 1a: hidden layers.  grid 64 = 8 batches x 8 row-groups, 256 thr
// ============================================================
__global__ __launch_bounds__(256) void k_hidden(
    const float* __restrict__ F,
    const float* __restrict__ bw1, const float* __restrict__ bb1,
    const float* __restrict__ cw1, const float* __restrict__ cb1,
    float* __restrict__ ws)
{
    __shared__ float sF[8 * 256];
    const int blk = blockIdx.x;
    const int b   = blk >> 3;
    const int r0  = (blk & 7) * 8;     // first of 8 F-rows this block handles
    const int tid = threadIdx.x;

    float* wsH1 = ws + WS_H1;
    float* wsH2 = ws + WS_H2;

    const float* Fb = F + ((size_t)b * 64 + r0) * 256;
    for (int i = tid; i < 2048; i += 256) sF[i] = Fb[i];
    __syncthreads();

    // hidden1 = relu(F @ bw1 + bb1): rows r0..r0+8, 64 cols -> 512 elems
    for (int e = tid; e < 512; e += 256) {
        const int v = e >> 6, k = e & 63;
        const float* fr = sF + v * 256;
        float acc = bb1[k];
        #pragma unroll 8
        for (int j = 0; j < 256; ++j) acc = fmaf(fr[j], bw1[j * 64 + k], acc);
        wsH1[((size_t)b * 64 + r0 + v) * 64 + k] = fmaxf(acc, 0.f);
    }
    // hidden2 = relu(F @ cw1 + cb1): 8 rows x 128 cols -> 1024 elems
    for (int e = tid; e < 1024; e += 256) {
        const int v = e >> 7, k = e & 127;
        const float* fr = sF + v * 256;
        float acc = cb1[k];
        #pragma unroll 8
        for (int j = 0; j < 256; ++j) acc = fmaf(fr[j], cw1[j * 128 + k], acc);
        wsH2[((size_t)b * 64 + r0 + v) * 128 + k] = fmaxf(acc, 0.f);
    }
}

// ============================================================
// Kernel 1b: latent, basis, Y(S2), coeffs, E, A/B.  grid 8, 512 thr
// ============================================================
__global__ __launch_bounds__(512) void k_coeffs(
    const float* __restrict__ ws_in,
    const float* __restrict__ S2,
    const float* __restrict__ bw2, const float* __restrict__ bb2,
    const float* __restrict__ cw2, const float* __restrict__ cb2,
    const float* __restrict__ iw,
    float* __restrict__ ws_out, float* __restrict__ outE)
{
    __shared__ float sH2[64 * 128];   // 32 KB
    __shared__ float sLat[64 * 64];   // 16 KB
    __shared__ float sY[64 * 16];     // 4 KB
    __shared__ float sBas[64 * 3];
    __shared__ float sC[16 * 64];
    __shared__ float sE[9];

    const int b = blockIdx.x, tid = threadIdx.x;
    const float* wsH1 = ws_in + WS_H1;
    const float* wsH2 = ws_in + WS_H2;
    float* wsC  = ws_out + WS_C;
    float* wsAB = ws_out + WS_AB;

    const float* H2b = wsH2 + (size_t)b * 8192;
    for (int i = tid; i < 8192; i += 512) sH2[i] = H2b[i];

    // Y basis on sphere points (S2 already unit vectors)
    if (tid < 64) {
        const float x = S2[tid * 3 + 0], y = S2[tid * 3 + 1], z = S2[tid * 3 + 2];
        float* Yv = sY + tid * 16;
        Yv[0]  = 0.28209479f;
        Yv[1]  = 0.48860251f * y;
        Yv[2]  = 0.48860251f * z;
        Yv[3]  = 0.48860251f * x;
        Yv[4]  = 1.09254843f * x * y;
        Yv[5]  = 1.09254843f * y * z;
        Yv[6]  = 0.31539157f * (3.f * z * z - 1.f);
        Yv[7]  = 1.09254843f * x * z;
        Yv[8]  = 0.54627421f * (x * x - y * y);
        Yv[9]  = 0.59004359f * y * (3.f * x * x - y * y);
        Yv[10] = 2.89061144f * x * y * z;
        Yv[11] = 0.45704579f * y * (5.f * z * z - 1.f);
        Yv[12] = 0.37317633f * z * (5.f * z * z - 3.f);
        Yv[13] = 0.45704579f * x * (5.f * z * z - 1.f);
        Yv[14] = 1.44530572f * z * (x * x - y * y);
        Yv[15] = 0.59004359f * x * (x * x - 3.f * y * y);
    }

    // basis = hidden1 @ bw2 + bb2 : [64,3] -> regs (H1 read from global)
    float breg = 0.f;
    if (tid < 192) {
        const int v = tid / 3, c = tid % 3;
        const float* h1 = wsH1 + ((size_t)b * 64 + v) * 64;
        float acc = bb2[c];
        #pragma unroll 8
        for (int k = 0; k < 64; ++k) acc = fmaf(h1[k], bw2[k * 3 + c], acc);
        breg = acc;
    }
    __syncthreads();   // sH2, sY ready

    if (tid < 192) sBas[tid] = breg;

    // latent = hidden2 @ cw2 + cb2 : [64,64]
    for (int e = tid; e < 4096; e += 512) {
        const int v = e >> 6, i = e & 63;
        const float* h2 = sH2 + v * 128;
        float acc = cb2[i];
        #pragma unroll 8
        for (int k = 0; k < 128; ++k) acc = fmaf(h2[k], cw2[k * 64 + i], acc);
        sLat[e] = acc;
    }
    __syncthreads();   // sLat, sBas ready

    // coeffs[m,i] = quad * sum_v Y[v,m] * lat[v,i] ; m in [0,16)
    for (int o = tid; o < 1024; o += 512) {
        const int m = o >> 6, i = o & 63;
        float acc = 0.f;
        #pragma unroll 8
        for (int v = 0; v < 64; ++v) acc = fmaf(sY[v * 16 + m], sLat[v * 64 + i], acc);
        acc *= QUAD;
        sC[o] = acc;
        wsC[(size_t)b * 1024 + o] = acc;
    }
    // E row sums (unnormalized)
    if (tid < 9) {
        const int m = tid / 3, c = tid % 3;
        float acc = 0.f;
        for (int v = 0; v < 64; ++v) acc = fmaf(sY[v * 16 + 1 + m], sBas[v * 3 + c], acc);
        sE[tid] = acc * QUAD;
    }
    __syncthreads();   // sC, sE ready

    if (tid < 9) {
        const int m = tid / 3;
        const float e0 = sE[m * 3 + 0], e1 = sE[m * 3 + 1], e2 = sE[m * 3 + 2];
        const float n = sqrtf(e0 * e0 + e1 * e1 + e2 * e2);
        outE[b * 9 + tid] = sE[tid] / fmaxf(n, 1e-6f);
    }
    // A/B: fold points_inv @ iw.  pts[c] = ib[c] + sum_m P1_m*(A[m,c] + r2*B[m,c])
    // A[m,c] = sum_i coeffs1[m,i]*iw[(2i+0)*3+c] ; B uses 2i+1
    if (tid < 18) {
        const int which = tid / 9, mc = tid % 9;
        const int m = mc / 3, c = mc % 3;
        float acc = 0.f;
        #pragma unroll 8
        for (int i = 0; i < 64; ++i)
            acc = fmaf(sC[(1 + m) * 64 + i], iw[(2 * i + which) * 3 + c], acc);
        wsAB[b * 18 + tid] = acc;
    }
}

// ============================================================
// Kernel 2: per-point monomials, points_code, coords, grid-sample.
// grid 4096 = 8 batches x 512 groups of 64 points ; 384 threads (6 waves)
// ============================================================
template <int NM, int MOFF, bool HASJ>
__device__ __forceinline__ void phaseC(const float* __restrict__ sC,
                                       const float* __restrict__ sZ,
                                       float* __restrict__ out,
                                       size_t base, int i, int j)
{
    float cr[NM];
    #pragma unroll
    for (int m = 0; m < NM; ++m) cr[m] = sC[(MOFF + m) * 64 + i];
    #pragma unroll 4
    for (int v = 0; v < 64; ++v) {
        const float* Z = sZ + v * 17;
        float acc = 0.f;
        #pragma unroll
        for (int m = 0; m < NM; ++m) acc = fmaf(cr[m], Z[MOFF + m], acc);
        if (HASJ && j) acc *= Z[16];     // radial r^2 factor
        out[base + (size_t)v * 384] = acc;
    }
}

__global__ __launch_bounds__(384) void k_points(
    const float* __restrict__ x, const float* __restrict__ dens,
    const float* __restrict__ ws, const float* __restrict__ ib,
    float* __restrict__ out)
{
    __shared__ float sC[16 * 64];
    __shared__ float sAB[18];
    __shared__ float sZ[64 * 17];

    const int blk = blockIdx.x;       // b*512 + group
    const int b   = blk >> 9;
    const int v0  = (blk & 511) * 64;
    const int tid = threadIdx.x;

    const float* wsC  = ws + WS_C;
    const float* wsAB = ws + WS_AB;

    for (int i = tid; i < 1024; i += 384) sC[i] = wsC[(size_t)b * 1024 + i];
    if (tid < 18) sAB[tid] = wsAB[b * 18 + tid];

    if (tid < 64) {
        const int v = v0 + tid;
        const size_t g = (size_t)b * 32768 + v;
        const float px = x[g * 3 + 0], py = x[g * 3 + 1], pz = x[g * 3 + 2];
        const float r2 = px * px + py * py + pz * pz;
        const float r  = sqrtf(r2);
        const float inv = 1.f / fmaxf(r, 1e-6f);
        const float ux = px * inv, uy = py * inv, uz = pz * inv;
        float* Z = sZ + tid * 17;
        Z[0] = 0.28209479f;
        Z[1] = 0.48860251f * uy * r;
        Z[2] = 0.48860251f * uz * r;
        Z[3] = 0.48860251f * ux * r;
        Z[4] = 1.09254843f * ux * uy * r2;
        Z[5] = 1.09254843f * uy * uz * r2;
        Z[6] = 0.31539157f * (3.f * uz * uz - 1.f) * r2;
        Z[7] = 1.09254843f * ux * uz * r2;
        Z[8] = 0.54627421f * (ux * ux - uy * uy) * r2;
        const float r3 = r2 * r;
        Z[9]  = 0.59004359f * uy * (3.f * ux * ux - uy * uy) * r3;
        Z[10] = 2.89061144f * ux * uy * uz * r3;
        Z[11] = 0.45704579f * uy * (5.f * uz * uz - 1.f) * r3;
        Z[12] = 0.37317633f * uz * (5.f * uz * uz - 3.f) * r3;
        Z[13] = 0.45704579f * ux * (5.f * uz * uz - 1.f) * r3;
        Z[14] = 1.44530572f * uz * (ux * ux - uy * uy) * r3;
        Z[15] = 0.59004359f * ux * (ux * ux - 3.f * uy * uy) * r3;
        Z[16] = r2;

        // pts = points_inv @ iw + ib, folded through A/B
        float pt[3];
        #pragma unroll
        for (int c = 0; c < 3; ++c) {
            float acc = ib[c];
            #pragma unroll
            for (int m = 0; m < 3; ++m)
                acc += Z[1 + m] * (sAB[m * 3 + c] + r2 * sAB[9 + m * 3 + c]);
            pt[c] = acc;
            out[OFF_COORD + g * 3 + c] = acc;
        }

        // grid_sample_3d: align_corners=True, zeros padding; vol 32^3
        const float ix = (pt[0] + 1.f) * 0.5f * 31.f;
        const float iy = (pt[1] + 1.f) * 0.5f * 31.f;
        const float iz = (pt[2] + 1.f) * 0.5f * 31.f;
        const float x0f = floorf(ix), y0f = floorf(iy), z0f = floorf(iz);
        const float wx = ix - x0f, wy = iy - y0f, wz = iz - z0f;
        const int x0 = (int)x0f, y0 = (int)y0f, z0 = (int)z0f;
        const float* volb = dens + (size_t)b * 32768;
        float s = 0.f;
        #pragma unroll
        for (int dz = 0; dz < 2; ++dz) {
            const int zi = z0 + dz;
            const float wzz = dz ? wz : 1.f - wz;
            #pragma unroll
            for (int dy = 0; dy < 2; ++dy) {
                const int yi = y0 + dy;
                const float wyy = dy ? wy : 1.f - wy;
                #pragma unroll
                for (int dx = 0; dx < 2; ++dx) {
                    const int xi = x0 + dx;
                    const float wxx = dx ? wx : 1.f - wx;
                    if (zi >= 0 && zi < 32 && yi >= 0 && yi < 32 && xi >= 0 && xi < 32)
                        s += wzz * wyy * wxx * volb[zi * 1024 + yi * 32 + xi];
                }
            }
        }
        out[g] = s;
    }
    __syncthreads();

    // phase C: each thread owns one of 384 output channels, loops 64 points.
    // l-blocks: [0,128)=l0 (i*2+j), [128,256)=l1 (i*2+j), [256,320)=l2, [320,384)=l3
    const int c = tid;
    const size_t base = OFF_CODE + ((size_t)b * 32768 + v0) * 384 + c;
    if (c < 128) {
        phaseC<1, 0, true>(sC, sZ, out, base, c >> 1, c & 1);
    } else if (c < 256) {
        const int cc = c - 128;
        phaseC<3, 1, true>(sC, sZ, out, base, cc >> 1, cc & 1);
    } else if (c < 320) {
        phaseC<5, 4, false>(sC, sZ, out, base, c - 256, 0);
    } else {
        phaseC<7, 9, false>(sC, sZ, out, base, c - 320, 0);
    }
}

// ============================================================
extern "C" void kernel_launch(void* const* d_in, const int* in_sizes, int n_in,
                              void* d_out, int out_size, void* d_ws, size_t ws_size,
                              hipStream_t stream) {
    const float* x    = (const float*)d_in[0];
    const float* dens = (const float*)d_in[1];
    const float* F    = (const float*)d_in[2];
    const float* S2   = (const float*)d_in[3];
    const float* bw1  = (const float*)d_in[4];
    const float* bb1  = (const float*)d_in[5];
    const float* bw2  = (const float*)d_in[6];
    const float* bb2  = (const float*)d_in[7];
    const float* cw1  = (const float*)d_in[8];
    const float* cb1  = (const float*)d_in[9];
    const float* cw2  = (const float*)d_in[10];
    const float* cb2  = (const float*)d_in[11];
    const float* iw   = (const float*)d_in[12];
    const float* ib   = (const float*)d_in[13];
    float* out = (float*)d_out;
    float* ws  = (float*)d_ws;

    k_hidden<<<64, 256, 0, stream>>>(F, bw1, bb1, cw1, cb1, ws);
    k_coeffs<<<8, 512, 0, stream>>>(ws, S2, bw2, bb2, cw2, cb2, iw, ws, out + OFF_E);
    k_points<<<4096, 384, 0, stream>>>(x, dens, ws, ib, out);
}